// Round 8
// baseline (5823.359 us; speedup 1.0000x reference)
//
#include <hip/hip_runtime.h>
#include <cstdint>
#include <cmath>
#include <utility>
#include <complex>

static constexpr int Nd = 1024;
static constexpr size_t NN = (size_t)Nd * Nd;
static constexpr uint32_t NOISE_H = 4718592u; // 9*N*N/2

typedef _Float16 f16x8 __attribute__((ext_vector_type(8)));
typedef float f32x4 __attribute__((ext_vector_type(4)));

// ------------------------- threefry2x32-20 (jax classic) -------------------------
__device__ __forceinline__ uint32_t rotl32(uint32_t v, int r) { return (v << r) | (v >> (32 - r)); }

__device__ __forceinline__ void tf2x32(uint32_t x0, uint32_t x1, uint32_t& o0, uint32_t& o1) {
  const uint32_t ks0 = 0u, ks1 = 42u, ks2 = 0x1BD11BDAu ^ 42u;
  x0 += ks0; x1 += ks1;
  x0 += x1; x1 = rotl32(x1, 13); x1 ^= x0;
  x0 += x1; x1 = rotl32(x1, 15); x1 ^= x0;
  x0 += x1; x1 = rotl32(x1, 26); x1 ^= x0;
  x0 += x1; x1 = rotl32(x1, 6);  x1 ^= x0;
  x0 += ks1; x1 += ks2 + 1u;
  x0 += x1; x1 = rotl32(x1, 17); x1 ^= x0;
  x0 += x1; x1 = rotl32(x1, 29); x1 ^= x0;
  x0 += x1; x1 = rotl32(x1, 16); x1 ^= x0;
  x0 += x1; x1 = rotl32(x1, 24); x1 ^= x0;
  x0 += ks2; x1 += ks0 + 2u;
  x0 += x1; x1 = rotl32(x1, 13); x1 ^= x0;
  x0 += x1; x1 = rotl32(x1, 15); x1 ^= x0;
  x0 += x1; x1 = rotl32(x1, 26); x1 ^= x0;
  x0 += x1; x1 = rotl32(x1, 6);  x1 ^= x0;
  x0 += ks0; x1 += ks1 + 3u;
  x0 += x1; x1 = rotl32(x1, 17); x1 ^= x0;
  x0 += x1; x1 = rotl32(x1, 29); x1 ^= x0;
  x0 += x1; x1 = rotl32(x1, 16); x1 ^= x0;
  x0 += x1; x1 = rotl32(x1, 24); x1 ^= x0;
  x0 += ks1; x1 += ks2 + 4u;
  x0 += x1; x1 = rotl32(x1, 13); x1 ^= x0;
  x0 += x1; x1 = rotl32(x1, 15); x1 ^= x0;
  x0 += x1; x1 = rotl32(x1, 26); x1 ^= x0;
  x0 += x1; x1 = rotl32(x1, 6);  x1 ^= x0;
  x0 += ks2; x1 += ks0 + 5u;
  o0 = x0; o1 = x1;
}

// ------------------------- split helpers -------------------------
__device__ __forceinline__ void split_store4(_Float16* hi, _Float16* lo, const float4 v) {
  union U { _Float16 h[4]; short4 s; };
  U uh, ul;
  uh.h[0] = (_Float16)v.x; ul.h[0] = (_Float16)(v.x - (float)uh.h[0]);
  uh.h[1] = (_Float16)v.y; ul.h[1] = (_Float16)(v.y - (float)uh.h[1]);
  uh.h[2] = (_Float16)v.z; ul.h[2] = (_Float16)(v.z - (float)uh.h[2]);
  uh.h[3] = (_Float16)v.w; ul.h[3] = (_Float16)(v.w - (float)uh.h[3]);
  *(short4*)hi = uh.s;
  *(short4*)lo = ul.s;
}

// ---------- NT split-f16 MFMA GEMM, single-buffer 40960B LDS (3 blocks/CU), 2 barriers/iter ----------
// C = lam*(alpha*A@Beff^T + beta*R + gamma*I + delta*R2); COMB=1: Beff = cb1*B + cb2*B2.
template <int COMB>
__global__ __launch_bounds__(256) void gemm_nt(const float* __restrict__ A, const float* __restrict__ B,
                                               const float* __restrict__ B2,
                                               const float* R, const float* R2, float* __restrict__ C,
                                               float alpha, float beta, float gamma, float delta,
                                               float cb1, float cb2, const float* lam) {
  constexpr int KP = 40; // 80 B rows: b128-aligned frags, non-pow2 banks
  const int bz = blockIdx.z;
  A += (size_t)bz * NN; B += (size_t)bz * NN; C += (size_t)bz * NN;
  R += (size_t)bz * NN; R2 += (size_t)bz * NN;
  if (COMB) B2 += (size_t)bz * NN;
  __shared__ _Float16 Ah[128 * KP], Al[128 * KP], Bh[128 * KP], Bl[128 * KP]; // 40960 B

  const int tid = threadIdx.x;
  const int bm = blockIdx.y * 128, bn = blockIdx.x * 128;
  const int lane = tid & 63, w = tid >> 6;
  const int wr = (w >> 1) * 64, wc = (w & 1) * 64;
  const int m0 = lane & 15, quad = lane >> 4;
  const int srow = tid >> 3, sq = tid & 7;

  f32x4 acc[4][4];
#pragma unroll
  for (int i = 0; i < 4; i++)
#pragma unroll
    for (int j = 0; j < 4; j++) acc[i][j] = (f32x4){0.f, 0.f, 0.f, 0.f};

  float4 pa[4], pb[4];
  auto ldTiles = [&](int k0) {
#pragma unroll
    for (int r = 0; r < 4; r++) {
      pa[r] = *(const float4*)(A + (size_t)(bm + srow + 32 * r) * Nd + k0 + 4 * sq);
      float4 vb = *(const float4*)(B + (size_t)(bn + srow + 32 * r) * Nd + k0 + 4 * sq);
      if (COMB) {
        const float4 v2 = *(const float4*)(B2 + (size_t)(bn + srow + 32 * r) * Nd + k0 + 4 * sq);
        vb.x = cb1 * vb.x + cb2 * v2.x; vb.y = cb1 * vb.y + cb2 * v2.y;
        vb.z = cb1 * vb.z + cb2 * v2.z; vb.w = cb1 * vb.w + cb2 * v2.w;
      }
      pb[r] = vb;
    }
  };
  auto stTiles = [&]() {
#pragma unroll
    for (int r = 0; r < 4; r++) {
      const int ro = (srow + 32 * r) * KP + 4 * sq;
      split_store4(&Ah[ro], &Al[ro], pa[r]);
      split_store4(&Bh[ro], &Bl[ro], pb[r]);
    }
  };

  ldTiles(0);
  for (int k0 = 0; k0 < Nd; k0 += 32) {
    if (k0) __syncthreads(); // all waves done reading previous tile
    stTiles();
    __syncthreads();
    if (k0 + 32 < Nd) ldTiles(k0 + 32); // prefetch overlaps frag reads + MFMA
    f16x8 ah[4], al4[4], bh[4], bl[4];
#pragma unroll
    for (int i = 0; i < 4; i++) {
      const int ra = (wr + i * 16 + m0) * KP + quad * 8;
      const int rb = (wc + i * 16 + m0) * KP + quad * 8;
      ah[i]  = *(const f16x8*)&Ah[ra];
      al4[i] = *(const f16x8*)&Al[ra];
      bh[i]  = *(const f16x8*)&Bh[rb];
      bl[i]  = *(const f16x8*)&Bl[rb];
    }
#pragma unroll
    for (int i = 0; i < 4; i++)
#pragma unroll
      for (int j = 0; j < 4; j++) {
        acc[i][j] = __builtin_amdgcn_mfma_f32_16x16x32_f16(ah[i], bh[j], acc[i][j], 0, 0, 0);
        acc[i][j] = __builtin_amdgcn_mfma_f32_16x16x32_f16(ah[i], bl[j], acc[i][j], 0, 0, 0);
        acc[i][j] = __builtin_amdgcn_mfma_f32_16x16x32_f16(al4[i], bh[j], acc[i][j], 0, 0, 0);
      }
  }

  const float l = lam ? lam[bz] : 1.0f;
  const bool useR = (beta != 0.0f);
  const bool useR2 = (delta != 0.0f);
#pragma unroll
  for (int i = 0; i < 4; i++) {
#pragma unroll
    for (int j = 0; j < 4; j++) {
      const int col = bn + wc + j * 16 + m0;
#pragma unroll
      for (int reg = 0; reg < 4; reg++) {
        const int row = bm + wr + i * 16 + quad * 4 + reg;
        float v = alpha * acc[i][j][reg];
        if (useR) v = fmaf(beta, R[(size_t)row * Nd + col], v);
        if (useR2) v = fmaf(delta, R2[(size_t)row * Nd + col], v);
        if (gamma != 0.0f && row == col) v += gamma;
        C[(size_t)row * Nd + col] = l * v;
      }
    }
  }
}

// ---------- Gram split-f16 MFMA GEMM (A^T @ B), scratch transpose path (r5-proven, unchanged) ----------
__global__ __launch_bounds__(256) void gemm_tn(const float* __restrict__ A, const float* __restrict__ B,
                                               const float* R, const float* R2, float* __restrict__ C,
                                               float alpha, float beta, float gamma, float delta,
                                               const float* lam) {
  constexpr int KP = 40;
  constexpr int SP = 130;
  const int bz = blockIdx.z;
  A += (size_t)bz * NN; B += (size_t)bz * NN; C += (size_t)bz * NN;
  R += (size_t)bz * NN; R2 += (size_t)bz * NN;
  __shared__ _Float16 Ah[128 * KP], Al[128 * KP], Bh[128 * KP], Bl[128 * KP];
  __shared__ float scr[2 * 32 * SP];
  float* scrA = scr;
  float* scrB = scr + 32 * SP;

  const int tid = threadIdx.x;
  const int bm = blockIdx.y * 128, bn = blockIdx.x * 128;
  const int lane = tid & 63, w = tid >> 6;
  const int wr = (w >> 1) * 64, wc = (w & 1) * 64;
  const int m0 = lane & 15, quad = lane >> 4;

  f32x4 acc[4][4];
#pragma unroll
  for (int i = 0; i < 4; i++)
#pragma unroll
    for (int j = 0; j < 4; j++) acc[i][j] = (f32x4){0.f, 0.f, 0.f, 0.f};

  const int n4 = tid & 31, kk8 = tid >> 5;
  const int sq2 = tid & 7, nr = tid >> 3;

  float4 pfA[4], pfB[4];
#pragma unroll
  for (int r = 0; r < 4; r++) {
    pfA[r] = *(const float4*)(A + (size_t)(kk8 + 8 * r) * Nd + bm + 4 * n4);
    pfB[r] = *(const float4*)(B + (size_t)(kk8 + 8 * r) * Nd + bn + 4 * n4);
  }

  for (int k0 = 0; k0 < Nd; k0 += 32) {
    __syncthreads();
#pragma unroll
    for (int r = 0; r < 4; r++) {
      const int kk = kk8 + 8 * r;
      *(float2*)&scrA[kk * SP + 4 * n4] = make_float2(pfA[r].x, pfA[r].y);
      *(float2*)&scrA[kk * SP + 4 * n4 + 2] = make_float2(pfA[r].z, pfA[r].w);
      *(float2*)&scrB[kk * SP + 4 * n4] = make_float2(pfB[r].x, pfB[r].y);
      *(float2*)&scrB[kk * SP + 4 * n4 + 2] = make_float2(pfB[r].z, pfB[r].w);
    }
    __syncthreads();
#pragma unroll
    for (int r = 0; r < 4; r++) {
      const int row = nr + 32 * r;
      union U { _Float16 h[4]; short4 s; } ph, pl, qh, ql;
#pragma unroll
      for (int j = 0; j < 4; j++) {
        const float fa = scrA[(4 * sq2 + j) * SP + row];
        ph.h[j] = (_Float16)fa;
        pl.h[j] = (_Float16)(fa - (float)ph.h[j]);
        const float fb = scrB[(4 * sq2 + j) * SP + row];
        qh.h[j] = (_Float16)fb;
        ql.h[j] = (_Float16)(fb - (float)qh.h[j]);
      }
      *(short4*)&Ah[row * KP + 4 * sq2] = ph.s;
      *(short4*)&Al[row * KP + 4 * sq2] = pl.s;
      *(short4*)&Bh[row * KP + 4 * sq2] = qh.s;
      *(short4*)&Bl[row * KP + 4 * sq2] = ql.s;
    }
    if (k0 + 32 < Nd) {
      const int kn = k0 + 32;
#pragma unroll
      for (int r = 0; r < 4; r++) {
        pfA[r] = *(const float4*)(A + (size_t)(kn + kk8 + 8 * r) * Nd + bm + 4 * n4);
        pfB[r] = *(const float4*)(B + (size_t)(kn + kk8 + 8 * r) * Nd + bn + 4 * n4);
      }
    }
    __syncthreads();
    f16x8 ah[4], al4[4], bh[4], bl[4];
#pragma unroll
    for (int i = 0; i < 4; i++) {
      ah[i]  = *(const f16x8*)&Ah[(wr + i * 16 + m0) * KP + quad * 8];
      al4[i] = *(const f16x8*)&Al[(wr + i * 16 + m0) * KP + quad * 8];
      bh[i]  = *(const f16x8*)&Bh[(wc + i * 16 + m0) * KP + quad * 8];
      bl[i]  = *(const f16x8*)&Bl[(wc + i * 16 + m0) * KP + quad * 8];
    }
#pragma unroll
    for (int i = 0; i < 4; i++)
#pragma unroll
      for (int j = 0; j < 4; j++) {
        acc[i][j] = __builtin_amdgcn_mfma_f32_16x16x32_f16(ah[i], bh[j], acc[i][j], 0, 0, 0);
        acc[i][j] = __builtin_amdgcn_mfma_f32_16x16x32_f16(ah[i], bl[j], acc[i][j], 0, 0, 0);
        acc[i][j] = __builtin_amdgcn_mfma_f32_16x16x32_f16(al4[i], bh[j], acc[i][j], 0, 0, 0);
      }
  }

  const float l = lam ? lam[bz] : 1.0f;
  const bool useR = (beta != 0.0f);
  const bool useR2 = (delta != 0.0f);
#pragma unroll
  for (int i = 0; i < 4; i++) {
#pragma unroll
    for (int j = 0; j < 4; j++) {
      const int col = bn + wc + j * 16 + m0;
#pragma unroll
      for (int reg = 0; reg < 4; reg++) {
        const int row = bm + wr + i * 16 + quad * 4 + reg;
        float v = alpha * acc[i][j][reg];
        if (useR) v = fmaf(beta, R[(size_t)row * Nd + col], v);
        if (useR2) v = fmaf(delta, R2[(size_t)row * Nd + col], v);
        if (gamma != 0.0f && row == col) v += gamma;
        C[(size_t)row * Nd + col] = l * v;
      }
    }
  }
}

// ------------------------- small kernels -------------------------
__global__ void k_qsum(const float* __restrict__ Q, float* qsum) {
  __shared__ float red[256];
  const int m = blockIdx.x >> 5, chunk = blockIdx.x & 31;
  const float4* src = (const float4*)(Q + (size_t)m * NN) + (size_t)chunk * 8192 + threadIdx.x;
  float s = 0.f;
#pragma unroll 4
  for (int i = 0; i < 32; i++) {
    const float4 v = src[(size_t)i * 256];
    s += (v.x + v.y) + (v.z + v.w);
  }
  red[threadIdx.x] = s;
  __syncthreads();
  for (int st = 128; st; st >>= 1) {
    if (threadIdx.x < st) red[threadIdx.x] += red[threadIdx.x + st];
    __syncthreads();
  }
  if (threadIdx.x == 0) atomicAdd(&qsum[m], red[0]);
}

__global__ void k_qn(const float* __restrict__ Qbase, const float* __restrict__ qsum, float* __restrict__ S0,
                     int base) {
  size_t id = (size_t)blockIdx.x * 256 + threadIdx.x;
  int b = (int)(id / NN);
  size_t e = id % NN;
  int mi = base + b;
  int i = mi / 3;
  uint32_t nid = (uint32_t)((size_t)mi * NN + e);
  uint32_t pk = nid < NOISE_H ? nid : nid - NOISE_H;
  uint32_t o0, o1;
  tf2x32(pk, pk + NOISE_H, o0, o1);
  uint32_t bits = nid < NOISE_H ? o0 : o1;
  float un = __uint_as_float((bits >> 9) | 0x3F800000u) - 1.0f;
  float coef = 0.01f * qsum[i] * (1.0f / 1048576.0f);
  S0[id] = Qbase[(size_t)i * NN + e] + coef * un;
}

__global__ void k_vinit(float* v) {
  size_t id = (size_t)blockIdx.x * 256 + threadIdx.x;
  uint32_t h = (uint32_t)(id % Nd) * 2654435761u ^ 0x9E3779B9u;
  h ^= h >> 16; h *= 0x85EBCA6Bu; h ^= h >> 13;
  v[id] = (float)(h & 0xFFFFu) / 65536.0f - 0.5f;
}

__global__ __launch_bounds__(256) void k_matvec(const float* __restrict__ Qn, const float* __restrict__ v,
                                                float* __restrict__ w) {
  int b = blockIdx.y;
  const float* M = Qn + (size_t)b * NN;
  const float* vb = v + (size_t)b * Nd;
  int wave = threadIdx.x >> 6, lane = threadIdx.x & 63;
  int row = blockIdx.x * 4 + wave;
  const float* rp = M + (size_t)row * Nd;
  float s = 0.f;
  for (int c = lane; c < Nd; c += 64) s = fmaf(rp[c], vb[c], s);
#pragma unroll
  for (int off = 32; off; off >>= 1) s += __shfl_down(s, off, 64);
  if (lane == 0) w[(size_t)b * Nd + row] = s;
}

__global__ __launch_bounds__(256) void k_matvecT(const float* __restrict__ Qn, const float* __restrict__ w,
                                                 float* __restrict__ u) {
  int b = blockIdx.y;
  const float* M = Qn + (size_t)b * NN;
  const float* wb = w + (size_t)b * Nd;
  int col = blockIdx.x * 256 + threadIdx.x;
  float s = 0.f;
  for (int r = 0; r < Nd; r++) s = fmaf(M[(size_t)r * Nd + col], wb[r], s);
  u[(size_t)b * Nd + col] = s;
}

__global__ void k_normalize(const float* __restrict__ u, float* __restrict__ v, float* theta, float* invth,
                            float* tau, float Gc, int last) {
  int b = blockIdx.x;
  const float* ub = u + (size_t)b * Nd;
  __shared__ float red[256];
  float s = 0.f;
  for (int i = threadIdx.x; i < Nd; i += 256) s = fmaf(ub[i], ub[i], s);
  red[threadIdx.x] = s;
  __syncthreads();
  for (int st = 128; st; st >>= 1) {
    if (threadIdx.x < st) red[threadIdx.x] += red[threadIdx.x + st];
    __syncthreads();
  }
  float n2 = red[0];
  float rn = rsqrtf(n2);
  for (int i = threadIdx.x; i < Nd; i += 256) v[(size_t)b * Nd + i] = ub[i] * rn;
  if (last && threadIdx.x == 0) {
    float th = 1.02f * powf(n2, 0.25f);
    theta[b] = th;
    invth[b] = 1.0f / th;
    tau[b] = th / Gc;
  }
}

__global__ void k_scale(const float* __restrict__ src, const float* __restrict__ invth, float* __restrict__ dst) {
  size_t id = (size_t)blockIdx.x * 256 + threadIdx.x;
  int b = (int)(id / NN);
  dst[id] = src[id] * invth[b];
}

__global__ void k_zcomb(const float* __restrict__ X, const float* __restrict__ Y, const float* __restrict__ tau,
                        float* __restrict__ Z) {
  size_t id = (size_t)blockIdx.x * 256 + threadIdx.x;
  int b = (int)(id / NN);
  Z[id] = tau[b] * (1.5f * X[id] - 0.5f * Y[id]);
}

// dst = ca*A + cb*B + cd*I
__global__ void k_combo(const float* __restrict__ A, const float* __restrict__ B, float* __restrict__ dst,
                        float ca, float cb, float cd) {
  size_t id = (size_t)blockIdx.x * 256 + threadIdx.x;
  size_t e = id % NN;
  int row = (int)(e >> 10), col = (int)(e & 1023);
  float v = ca * A[id] + cb * B[id];
  if (row == col) v += cd;
  dst[id] = v;
}

// out (+)= sum_b 0.5*a0[i,j]*a1[j]*M[b]
__global__ void k_acc(const float* __restrict__ M, const float* __restrict__ a0, const float* __restrict__ a1,
                      float* __restrict__ out, int base, int g, int accum) {
  size_t e = (size_t)blockIdx.x * 256 + threadIdx.x;
  float s = accum ? out[e] : 0.f;
  for (int b = 0; b < g; b++) {
    int gi = base + b, i = gi / 3, j = gi % 3;
    s += 0.5f * a0[i * 3 + j] * a1[j] * M[(size_t)b * NN + e];
  }
  out[e] = s;
}

// ------------------------- host: solver + fits + roots -------------------------
static void solveN(double* M, double* r, double* x, int n) {
  for (int c = 0; c < n; c++) {
    int p = c;
    for (int i = c + 1; i < n; i++)
      if (fabs(M[i * n + c]) > fabs(M[p * n + c])) p = i;
    if (p != c) {
      for (int j = 0; j < n; j++) std::swap(M[c * n + j], M[p * n + j]);
      std::swap(r[c], r[p]);
    }
    double d = M[c * n + c];
    for (int i = c + 1; i < n; i++) {
      double f = M[i * n + c] / d;
      for (int j = c; j < n; j++) M[i * n + j] -= f * M[c * n + j];
      r[i] -= f * r[c];
    }
  }
  for (int c = n - 1; c >= 0; --c) {
    double s = r[c];
    for (int j = c + 1; j < n; j++) s -= M[c * n + j] * x[j];
    x[c] = s / M[c * n + c];
  }
}

static void fit_cheb(double* cq, double aQ, double bQ, double cQ, double Gcomp, double zmax) {
  const double theta_hat = 2660.0;
  const double tau_hat = theta_hat / Gcomp;
  const double wmax = zmax * zmax;
  double Mm[14 * 14] = {0}, rr[14] = {0}, sol[14];
  auto add = [&](double z, double t, double wgt) {
    double uu = 2.0 * z * z / wmax - 1.0;
    double T[14];
    T[0] = 1; T[1] = uu;
    for (int k = 2; k < 14; k++) T[k] = 2.0 * uu * T[k - 1] - T[k - 2];
    double ph[14];
    for (int k = 0; k < 14; k++) ph[k] = (z / zmax) * T[k];
    for (int a = 0; a < 14; a++) {
      rr[a] += wgt * t * ph[a];
      for (int b = 0; b < 14; b++) Mm[a * 14 + b] += wgt * ph[a] * ph[b];
    }
  };
  const int NS = 2600;
  const double lx0 = -5.0, lx1 = log10(1.05);
  for (int si = 0; si < NS; si++) {
    double x = pow(10.0, lx0 + (lx1 - lx0) * si / (NS - 1));
    double y = x;
    for (int q = 0; q < 4; q++) { double y2 = y * y; y = y * (aQ + y2 * (bQ + y2 * cQ)); }
    y = y * (1.5 - 0.5 * y * y);
    double z = tau_hat * y;
    double t = tanh(0.5 * theta_hat * x);
    add(z, t, (t > 0.9999) ? 2.0 : 1.0);
  }
  for (int si = 0; si < 400; si++) { double z = 12.0 + (zmax - 12.0) * si / 399.0; add(z, 1.0, 2.0); }
  solveN(Mm, rr, sol, 14);
  for (int k = 0; k < 14; k++) cq[k] = sol[k] / zmax;
}

static void fit_polish(double* e) {
  double M[16] = {0}, r[4] = {0};
  for (int i = 0; i < 400; i++) {
    double y = 0.44 + (1.40 - 0.44) * i / 399.0;
    double t = 1.0 / sqrt(y);
    double ph[4] = {1.0, y, y * y, y * y * y};
    for (int a = 0; a < 4; a++) {
      r[a] += t * ph[a];
      for (int b = 0; b < 4; b++) M[a * 4 + b] += ph[a] * ph[b];
    }
  }
  solveN(M, r, e, 4);
}

// Durand-Kerner roots of real polynomial a[0..deg] (a[deg] = lead)
static bool poly_roots(const double* a, int deg, std::complex<double>* rt) {
  std::complex<double> z[16];
  for (int i = 0; i < deg; i++) z[i] = std::polar(1.2, 0.37 + 6.2831853 * i / deg);
  for (int it = 0; it < 2000; ++it) {
    double move = 0;
    for (int i = 0; i < deg; i++) {
      std::complex<double> p = a[deg];
      for (int k = deg - 1; k >= 0; --k) p = p * z[i] + a[k];
      std::complex<double> d(a[deg], 0.0);
      for (int j = 0; j < deg; j++)
        if (j != i) d *= (z[i] - z[j]);
      if (std::abs(d) < 1e-300) return false;
      std::complex<double> dz = p / d;
      z[i] -= dz;
      move += std::abs(dz);
    }
    if (move < 1e-13) break;
  }
  for (int i = 0; i < deg; i++) rt[i] = z[i];
  return true;
}

// ------------------------- launch -------------------------
extern "C" void kernel_launch(void* const* d_in, const int* in_sizes, int n_in, void* d_out, int out_size,
                              void* d_ws, size_t ws_size, hipStream_t stream) {
  const float* Us = (const float*)d_in[0];
  const float* Vs = (const float*)d_in[1];
  const float* al0 = (const float*)d_in[2];
  const float* al1 = (const float*)d_in[3];
  float* out = (float*)d_out;

  const double aQ = 3.4445, bQ = -4.7750, cQ = 2.0315;
  const double Gcomp = aQ * aQ * aQ * aQ * 1.5;
  const double zmax = 14.5, wmax = zmax * zmax;
  double cheb[14], pol[4];
  fit_cheb(cheb, aQ, bQ, cQ, Gcomp, zmax);
  fit_polish(pol);

  // ---- factored form of p(y) = sum cheb[k] T_k(2y/wmax - 1), y = z^2 ----
  double tc[14][14] = {{0}};
  tc[0][0] = 1; tc[1][1] = 1;
  for (int k = 2; k < 14; k++)
    for (int j = 0; j < 14; j++) {
      double t = (j > 0 ? 2.0 * tc[k - 1][j - 1] : 0.0) - tc[k - 2][j];
      tc[k][j] = t;
    }
  double au[14] = {0};
  for (int k = 0; k < 14; k++)
    for (int j = 0; j <= k; j++) au[j] += cheb[k] * tc[k][j];
  int dg = 13;
  double amax = 0;
  for (int j = 0; j < 14; j++) amax = fmax(amax, fabs(au[j]));
  while (dg > 0 && fabs(au[dg]) < 1e-12 * amax) dg--;
  int nquad = 0, nlin = 0;
  double qp[7], qq[7], lin_r0 = 0;
  bool use_factored = false;
  {
    std::complex<double> rt[16];
    if (dg >= 1 && poly_roots(au, dg, rt)) {
      double yr[16];
      int nreal = 0;
      std::complex<double> yc[16];
      int ncm = 0;
      for (int i = 0; i < dg; i++) {
        std::complex<double> y = (rt[i] + 1.0) * (wmax / 2.0);
        if (fabs(y.imag()) < 1e-7 * (1.0 + fabs(y.real()))) yr[nreal++] = y.real();
        else yc[ncm++] = y;
      }
      for (int i = 0; i < ncm; i++)
        if (yc[i].imag() > 0) {
          qp[nquad] = -2.0 * yc[i].real();
          qq[nquad] = std::norm(yc[i]);
          nquad++;
        }
      for (int i = 0; i < nreal; i++)
        for (int j = i + 1; j < nreal; j++)
          if (yr[j] < yr[i]) std::swap(yr[i], yr[j]);
      int i = 0;
      for (; i + 1 < nreal; i += 2) {
        qp[nquad] = -(yr[i] + yr[i + 1]);
        qq[nquad] = yr[i] * yr[i + 1];
        nquad++;
      }
      if (i < nreal) { nlin = 1; lin_r0 = yr[i]; }
      if (2 * nquad + nlin == dg && nquad <= 7) {
        double lead_y = au[dg] * pow(2.0 / wmax, dg);
        double sigma = pow(fabs(lead_y), 1.0 / dg);
        double sgn = lead_y < 0 ? -1.0 : 1.0;
        double maxerr = 0, maxv = 0;
        for (int s = 0; s <= 256; s++) {
          double y = wmax * s / 256.0;
          double u = 2.0 * y / wmax - 1.0;
          double T0 = 1, T1 = u, pc = cheb[0] + cheb[1] * u;
          for (int k = 2; k < 14; k++) { double T2 = 2 * u * T1 - T0; pc += cheb[k] * T2; T0 = T1; T1 = T2; }
          double pf = nlin ? sgn * sigma * (y - lin_r0) : sgn;
          for (int qI = 0; qI < nquad; qI++) pf *= sigma * sigma * (y * y + qp[qI] * y + qq[qI]);
          maxerr = fmax(maxerr, fabs(pf - pc));
          maxv = fmax(maxv, fabs(pc));
        }
        if (maxerr < 1e-4 * fmax(maxv, 1.0)) use_factored = true;
        if (use_factored) { qq[6] = sigma; qp[6] = sgn; }
      }
    }
  }

  auto need = [&](int g) -> size_t { return 4ull * (3 * NN + 5ull * g * NN + 3ull * g * Nd + 64); };
  int g = 9;
  if (ws_size < need(9)) g = (ws_size >= need(3)) ? 3 : 1;
  const int groups = 9 / g;

  float* SQ = (float*)d_ws;
  float* S[5];
  for (int k = 0; k < 5; k++) S[k] = SQ + 3 * NN + (size_t)k * g * NN;
  float* pv = SQ + 3 * NN + 5ull * g * NN;
  float* pw = pv + (size_t)g * Nd;
  float* pu = pw + (size_t)g * Nd;
  float* qsum = pu + (size_t)g * Nd;
  float* th = qsum + 3;
  float* invth = th + g;
  float* tau = invth + g;

  auto nt = [&](const float* A, const float* B, const float* R, const float* R2, float* C,
                float al, float be, float ga, float de, const float* lam, int batch) {
    gemm_nt<0><<<dim3(8, 8, batch), 256, 0, stream>>>(A, B, nullptr, R, R2, C, al, be, ga, de, 0.f, 0.f, lam);
  };
  auto ntc = [&](const float* A, const float* B, const float* B2, const float* R2, float* C,
                 float al, float de, float cb1, float cb2, int batch) {
    gemm_nt<1><<<dim3(8, 8, batch), 256, 0, stream>>>(A, B, B2, A, R2, C, al, 0.f, 0.f, de, cb1, cb2, nullptr);
  };
  auto gram = [&](const float* A, const float* B, const float* R, const float* R2, float* C,
                  float al, float be, float ga, float de, const float* lam, int batch) {
    gemm_tn<<<dim3(8, 8, batch), 256, 0, stream>>>(A, B, R, R2, C, al, be, ga, de, lam);
  };

  hipMemsetAsync(qsum, 0, 3 * sizeof(float), stream);
  nt(Us, Vs, Us, Us, SQ, 1.f, 0.f, 0.f, 0.f, nullptr, 3); // Q_i = U_i V_i^T
  k_qsum<<<96, 256, 0, stream>>>(SQ, qsum);

  const int NSTEPS = 10;
  for (int grp = 0; grp < groups; ++grp) {
    const int base = grp * g;
    k_qn<<<g * 4096, 256, 0, stream>>>(SQ, qsum, S[0], base);
    k_vinit<<<(g * Nd) / 256, 256, 0, stream>>>(pv);
    for (int t = 0; t < 8; t++) {
      k_matvec<<<dim3(Nd / 4, g), 256, 0, stream>>>(S[0], pv, pw);
      k_matvecT<<<dim3(Nd / 256, g), 256, 0, stream>>>(S[0], pw, pu);
      k_normalize<<<g, 256, 0, stream>>>(pu, pv, th, invth, tau, (float)Gcomp, t == 7);
    }
    k_scale<<<g * 4096, 256, 0, stream>>>(S[0], invth, S[1]);
    float* Xc = S[1];
    float* Xa = S[2];
    // quintic NS steps: G = X^T X ; Y = X G ; X' = c*YG + b*Y + a*X
    for (int it = 0; it < NSTEPS; ++it) {
      gram(Xc, Xc, Xc, Xc, S[3], 1.f, 0.f, 0.f, 0.f, nullptr, g);            // G
      nt(Xc, S[3], Xc, Xc, S[4], 1.f, 0.f, 0.f, 0.f, nullptr, g);            // Y = X G (G sym)
      if (it == 4) // Z = tau*(1.5X - 0.5Y)
        k_zcomb<<<g * 4096, 256, 0, stream>>>(Xc, S[4], tau, S[0]);
      nt(S[4], S[3], S[4], Xc, Xa, (float)cQ, (float)bQ, 0.f, (float)aQ, nullptr, g);
      std::swap(Xc, Xa);
    }
    // degree-7 polish: P = X (e0 I + e1 G + e2 G^2 + e3 G^3)
    gram(Xc, Xc, Xc, Xc, S[3], 1.f, 0.f, 0.f, 0.f, nullptr, g);                                     // G
    nt(S[3], S[3], S[3], S[3], S[4], (float)pol[3], (float)pol[2], (float)pol[1], 0.f, nullptr, g); // K2
    nt(S[3], S[4], S[3], S[3], S[2], 1.f, 0.f, (float)pol[0], 0.f, nullptr, g);                     // K3
    nt(Xc, S[2], Xc, Xc, S[3], 1.f, 0.f, 0.f, 0.f, nullptr, g);                                     // P = X K3
    k_acc<<<4096, 256, 0, stream>>>(S[3], al0, al1, out, base, g, grp > 0);                         // out += w*P
    if (use_factored) {
      const double sigma = qq[6], sgn = qp[6];
      const double sg2 = sigma * sigma;
      gram(S[0], S[0], S[0], S[0], S[1], 1.f, 0.f, 0.f, 0.f, nullptr, g);       // Y = Z^T Z
      nt(S[1], S[1], S[1], S[1], S[2], 1.f, 0.f, 0.f, 0.f, nullptr, g);         // Y2 = Y*Y
      if (nlin)
        k_combo<<<g * 4096, 256, 0, stream>>>(S[1], S[1], S[3], (float)(sgn * sigma), 0.f,
                                              (float)(-sgn * sigma * lin_r0));
      else
        k_combo<<<g * 4096, 256, 0, stream>>>(S[1], S[1], S[3], 0.f, 0.f, (float)sgn);
      float* Mc = S[3];
      float* Md = S[4];
      for (int qI = 0; qI < nquad; qI++) {
        ntc(Mc, S[2], S[1], Mc, Md, 1.f, (float)(sg2 * qq[qI]), (float)sg2, (float)(sg2 * qp[qI]), g);
        std::swap(Mc, Md);
      }
      nt(S[0], Mc, S[0], S[0], Md, 1.f, 0.f, 0.f, 0.f, nullptr, g);             // T = Z q
      k_acc<<<4096, 256, 0, stream>>>(Md, al0, al1, out, base, g, 1);           // out += w*T
    } else {
      gram(S[0], S[0], S[0], S[0], S[1], (float)(2.0 / wmax), 0.f, -1.0f, 0.f, nullptr, g);
      float* Wm = S[1];
      nt(Wm, Wm, Wm, Wm, S[2], (float)(4.0 * cheb[13]), (float)(2.0 * cheb[12]),
         (float)(cheb[11] - cheb[13]), 0.f, nullptr, g);
      nt(Wm, S[2], Wm, Wm, S[4], 2.0f, (float)(-2.0 * cheb[13]),
         (float)(cheb[10] - cheb[12]), 0.f, nullptr, g);
      float* c1 = S[4];
      float* c2 = S[2];
      for (int k = 9; k >= 1; --k) {
        nt(Wm, c1, c2, Wm, c2, 2.0f, -1.0f, (float)cheb[k], 0.f, nullptr, g);
        std::swap(c1, c2);
      }
      nt(Wm, c1, c2, Wm, c2, 1.0f, -1.0f, (float)cheb[0], 0.f, nullptr, g);
      nt(S[0], c2, S[0], S[0], S[3], 1.f, 0.f, 0.f, 0.f, nullptr, g);           // T = Z q
      k_acc<<<4096, 256, 0, stream>>>(S[3], al0, al1, out, base, g, 1);
    }
  }
}

// Round 9
// 5397.387 us; speedup vs baseline: 1.0789x; 1.0789x over previous
//
#include <hip/hip_runtime.h>
#include <cstdint>
#include <cmath>
#include <utility>
#include <complex>

static constexpr int Nd = 1024;
static constexpr size_t NN = (size_t)Nd * Nd;
static constexpr uint32_t NOISE_H = 4718592u; // 9*N*N/2
static constexpr int NC = 11;                 // tanh Chebyshev coeff count (degree-21 odd)

typedef _Float16 f16x8 __attribute__((ext_vector_type(8)));
typedef float f32x4 __attribute__((ext_vector_type(4)));

// ------------------------- threefry2x32-20 (jax classic) -------------------------
__device__ __forceinline__ uint32_t rotl32(uint32_t v, int r) { return (v << r) | (v >> (32 - r)); }

__device__ __forceinline__ void tf2x32(uint32_t x0, uint32_t x1, uint32_t& o0, uint32_t& o1) {
  const uint32_t ks0 = 0u, ks1 = 42u, ks2 = 0x1BD11BDAu ^ 42u;
  x0 += ks0; x1 += ks1;
  x0 += x1; x1 = rotl32(x1, 13); x1 ^= x0;
  x0 += x1; x1 = rotl32(x1, 15); x1 ^= x0;
  x0 += x1; x1 = rotl32(x1, 26); x1 ^= x0;
  x0 += x1; x1 = rotl32(x1, 6);  x1 ^= x0;
  x0 += ks1; x1 += ks2 + 1u;
  x0 += x1; x1 = rotl32(x1, 17); x1 ^= x0;
  x0 += x1; x1 = rotl32(x1, 29); x1 ^= x0;
  x0 += x1; x1 = rotl32(x1, 16); x1 ^= x0;
  x0 += x1; x1 = rotl32(x1, 24); x1 ^= x0;
  x0 += ks2; x1 += ks0 + 2u;
  x0 += x1; x1 = rotl32(x1, 13); x1 ^= x0;
  x0 += x1; x1 = rotl32(x1, 15); x1 ^= x0;
  x0 += x1; x1 = rotl32(x1, 26); x1 ^= x0;
  x0 += x1; x1 = rotl32(x1, 6);  x1 ^= x0;
  x0 += ks0; x1 += ks1 + 3u;
  x0 += x1; x1 = rotl32(x1, 17); x1 ^= x0;
  x0 += x1; x1 = rotl32(x1, 29); x1 ^= x0;
  x0 += x1; x1 = rotl32(x1, 16); x1 ^= x0;
  x0 += x1; x1 = rotl32(x1, 24); x1 ^= x0;
  x0 += ks1; x1 += ks2 + 4u;
  x0 += x1; x1 = rotl32(x1, 13); x1 ^= x0;
  x0 += x1; x1 = rotl32(x1, 15); x1 ^= x0;
  x0 += x1; x1 = rotl32(x1, 26); x1 ^= x0;
  x0 += x1; x1 = rotl32(x1, 6);  x1 ^= x0;
  x0 += ks2; x1 += ks0 + 5u;
  o0 = x0; o1 = x1;
}

// ------------------------- split helpers -------------------------
__device__ __forceinline__ void split_store4(_Float16* hi, _Float16* lo, const float4 v) {
  union U { _Float16 h[4]; short4 s; };
  U uh, ul;
  uh.h[0] = (_Float16)v.x; ul.h[0] = (_Float16)(v.x - (float)uh.h[0]);
  uh.h[1] = (_Float16)v.y; ul.h[1] = (_Float16)(v.y - (float)uh.h[1]);
  uh.h[2] = (_Float16)v.z; ul.h[2] = (_Float16)(v.z - (float)uh.h[2]);
  uh.h[3] = (_Float16)v.w; ul.h[3] = (_Float16)(v.w - (float)uh.h[3]);
  *(short4*)hi = uh.s;
  *(short4*)lo = ul.s;
}

// ---------- NT split-f16 MFMA GEMM, single-buffer 40960B LDS, XCD-swizzled grid (64,1,batch) ----------
// by = bid&7 (A-slab per XCD, assuming linear-id%8 XCD round-robin), bx = bid>>3.
// C = lam*(alpha*A@Beff^T + beta*R + gamma*I + delta*R2); COMB=1: Beff = cb1*B + cb2*B2.
template <int COMB>
__global__ __launch_bounds__(256) void gemm_nt(const float* __restrict__ A, const float* __restrict__ B,
                                               const float* __restrict__ B2,
                                               const float* R, const float* R2, float* __restrict__ C,
                                               float alpha, float beta, float gamma, float delta,
                                               float cb1, float cb2, const float* lam) {
  constexpr int KP = 40;
  const int bz = blockIdx.z;
  A += (size_t)bz * NN; B += (size_t)bz * NN; C += (size_t)bz * NN;
  R += (size_t)bz * NN; R2 += (size_t)bz * NN;
  if (COMB) B2 += (size_t)bz * NN;
  __shared__ _Float16 Ah[128 * KP], Al[128 * KP], Bh[128 * KP], Bl[128 * KP]; // 40960 B

  const int tid = threadIdx.x;
  const int bid = blockIdx.x;
  const int bm = (bid & 7) * 128, bn = (bid >> 3) * 128; // same-XCD blocks share A-slab (L2)
  const int lane = tid & 63, w = tid >> 6;
  const int wr = (w >> 1) * 64, wc = (w & 1) * 64;
  const int m0 = lane & 15, quad = lane >> 4;
  const int srow = tid >> 3, sq = tid & 7;

  f32x4 acc[4][4];
#pragma unroll
  for (int i = 0; i < 4; i++)
#pragma unroll
    for (int j = 0; j < 4; j++) acc[i][j] = (f32x4){0.f, 0.f, 0.f, 0.f};

  float4 pa[4], pb[4];
  auto ldTiles = [&](int k0) {
#pragma unroll
    for (int r = 0; r < 4; r++) {
      pa[r] = *(const float4*)(A + (size_t)(bm + srow + 32 * r) * Nd + k0 + 4 * sq);
      float4 vb = *(const float4*)(B + (size_t)(bn + srow + 32 * r) * Nd + k0 + 4 * sq);
      if (COMB) {
        const float4 v2 = *(const float4*)(B2 + (size_t)(bn + srow + 32 * r) * Nd + k0 + 4 * sq);
        vb.x = cb1 * vb.x + cb2 * v2.x; vb.y = cb1 * vb.y + cb2 * v2.y;
        vb.z = cb1 * vb.z + cb2 * v2.z; vb.w = cb1 * vb.w + cb2 * v2.w;
      }
      pb[r] = vb;
    }
  };
  auto stTiles = [&]() {
#pragma unroll
    for (int r = 0; r < 4; r++) {
      const int ro = (srow + 32 * r) * KP + 4 * sq;
      split_store4(&Ah[ro], &Al[ro], pa[r]);
      split_store4(&Bh[ro], &Bl[ro], pb[r]);
    }
  };

  ldTiles(0);
  for (int k0 = 0; k0 < Nd; k0 += 32) {
    if (k0) __syncthreads();
    stTiles();
    __syncthreads();
    if (k0 + 32 < Nd) ldTiles(k0 + 32);
    f16x8 ah[4], al4[4], bh[4], bl[4];
#pragma unroll
    for (int i = 0; i < 4; i++) {
      const int ra = (wr + i * 16 + m0) * KP + quad * 8;
      const int rb = (wc + i * 16 + m0) * KP + quad * 8;
      ah[i]  = *(const f16x8*)&Ah[ra];
      al4[i] = *(const f16x8*)&Al[ra];
      bh[i]  = *(const f16x8*)&Bh[rb];
      bl[i]  = *(const f16x8*)&Bl[rb];
    }
#pragma unroll
    for (int i = 0; i < 4; i++)
#pragma unroll
      for (int j = 0; j < 4; j++) {
        acc[i][j] = __builtin_amdgcn_mfma_f32_16x16x32_f16(ah[i], bh[j], acc[i][j], 0, 0, 0);
        acc[i][j] = __builtin_amdgcn_mfma_f32_16x16x32_f16(ah[i], bl[j], acc[i][j], 0, 0, 0);
        acc[i][j] = __builtin_amdgcn_mfma_f32_16x16x32_f16(al4[i], bh[j], acc[i][j], 0, 0, 0);
      }
  }

  const float l = lam ? lam[bz] : 1.0f;
  const bool useR = (beta != 0.0f);
  const bool useR2 = (delta != 0.0f);
#pragma unroll
  for (int i = 0; i < 4; i++) {
#pragma unroll
    for (int j = 0; j < 4; j++) {
      const int col = bn + wc + j * 16 + m0;
#pragma unroll
      for (int reg = 0; reg < 4; reg++) {
        const int row = bm + wr + i * 16 + quad * 4 + reg;
        float v = alpha * acc[i][j][reg];
        if (useR) v = fmaf(beta, R[(size_t)row * Nd + col], v);
        if (useR2) v = fmaf(delta, R2[(size_t)row * Nd + col], v);
        if (gamma != 0.0f && row == col) v += gamma;
        C[(size_t)row * Nd + col] = l * v;
      }
    }
  }
}

// ---------- Gram split-f16 MFMA GEMM (A^T @ B), scratch transpose path, XCD-swizzled ----------
__global__ __launch_bounds__(256) void gemm_tn(const float* __restrict__ A, const float* __restrict__ B,
                                               const float* R, const float* R2, float* __restrict__ C,
                                               float alpha, float beta, float gamma, float delta,
                                               const float* lam) {
  constexpr int KP = 40;
  constexpr int SP = 130;
  const int bz = blockIdx.z;
  A += (size_t)bz * NN; B += (size_t)bz * NN; C += (size_t)bz * NN;
  R += (size_t)bz * NN; R2 += (size_t)bz * NN;
  __shared__ _Float16 Ah[128 * KP], Al[128 * KP], Bh[128 * KP], Bl[128 * KP];
  __shared__ float scr[2 * 32 * SP];
  float* scrA = scr;
  float* scrB = scr + 32 * SP;

  const int tid = threadIdx.x;
  const int bid = blockIdx.x;
  const int bm = (bid & 7) * 128, bn = (bid >> 3) * 128;
  const int lane = tid & 63, w = tid >> 6;
  const int wr = (w >> 1) * 64, wc = (w & 1) * 64;
  const int m0 = lane & 15, quad = lane >> 4;

  f32x4 acc[4][4];
#pragma unroll
  for (int i = 0; i < 4; i++)
#pragma unroll
    for (int j = 0; j < 4; j++) acc[i][j] = (f32x4){0.f, 0.f, 0.f, 0.f};

  const int n4 = tid & 31, kk8 = tid >> 5;
  const int sq2 = tid & 7, nr = tid >> 3;

  float4 pfA[4], pfB[4];
#pragma unroll
  for (int r = 0; r < 4; r++) {
    pfA[r] = *(const float4*)(A + (size_t)(kk8 + 8 * r) * Nd + bm + 4 * n4);
    pfB[r] = *(const float4*)(B + (size_t)(kk8 + 8 * r) * Nd + bn + 4 * n4);
  }

  for (int k0 = 0; k0 < Nd; k0 += 32) {
    __syncthreads();
#pragma unroll
    for (int r = 0; r < 4; r++) {
      const int kk = kk8 + 8 * r;
      *(float2*)&scrA[kk * SP + 4 * n4] = make_float2(pfA[r].x, pfA[r].y);
      *(float2*)&scrA[kk * SP + 4 * n4 + 2] = make_float2(pfA[r].z, pfA[r].w);
      *(float2*)&scrB[kk * SP + 4 * n4] = make_float2(pfB[r].x, pfB[r].y);
      *(float2*)&scrB[kk * SP + 4 * n4 + 2] = make_float2(pfB[r].z, pfB[r].w);
    }
    __syncthreads();
#pragma unroll
    for (int r = 0; r < 4; r++) {
      const int row = nr + 32 * r;
      union U { _Float16 h[4]; short4 s; } ph, pl, qh, ql;
#pragma unroll
      for (int j = 0; j < 4; j++) {
        const float fa = scrA[(4 * sq2 + j) * SP + row];
        ph.h[j] = (_Float16)fa;
        pl.h[j] = (_Float16)(fa - (float)ph.h[j]);
        const float fb = scrB[(4 * sq2 + j) * SP + row];
        qh.h[j] = (_Float16)fb;
        ql.h[j] = (_Float16)(fb - (float)qh.h[j]);
      }
      *(short4*)&Ah[row * KP + 4 * sq2] = ph.s;
      *(short4*)&Al[row * KP + 4 * sq2] = pl.s;
      *(short4*)&Bh[row * KP + 4 * sq2] = qh.s;
      *(short4*)&Bl[row * KP + 4 * sq2] = ql.s;
    }
    if (k0 + 32 < Nd) {
      const int kn = k0 + 32;
#pragma unroll
      for (int r = 0; r < 4; r++) {
        pfA[r] = *(const float4*)(A + (size_t)(kn + kk8 + 8 * r) * Nd + bm + 4 * n4);
        pfB[r] = *(const float4*)(B + (size_t)(kn + kk8 + 8 * r) * Nd + bn + 4 * n4);
      }
    }
    __syncthreads();
    f16x8 ah[4], al4[4], bh[4], bl[4];
#pragma unroll
    for (int i = 0; i < 4; i++) {
      ah[i]  = *(const f16x8*)&Ah[(wr + i * 16 + m0) * KP + quad * 8];
      al4[i] = *(const f16x8*)&Al[(wr + i * 16 + m0) * KP + quad * 8];
      bh[i]  = *(const f16x8*)&Bh[(wc + i * 16 + m0) * KP + quad * 8];
      bl[i]  = *(const f16x8*)&Bl[(wc + i * 16 + m0) * KP + quad * 8];
    }
#pragma unroll
    for (int i = 0; i < 4; i++)
#pragma unroll
      for (int j = 0; j < 4; j++) {
        acc[i][j] = __builtin_amdgcn_mfma_f32_16x16x32_f16(ah[i], bh[j], acc[i][j], 0, 0, 0);
        acc[i][j] = __builtin_amdgcn_mfma_f32_16x16x32_f16(ah[i], bl[j], acc[i][j], 0, 0, 0);
        acc[i][j] = __builtin_amdgcn_mfma_f32_16x16x32_f16(al4[i], bh[j], acc[i][j], 0, 0, 0);
      }
  }

  const float l = lam ? lam[bz] : 1.0f;
  const bool useR = (beta != 0.0f);
  const bool useR2 = (delta != 0.0f);
#pragma unroll
  for (int i = 0; i < 4; i++) {
#pragma unroll
    for (int j = 0; j < 4; j++) {
      const int col = bn + wc + j * 16 + m0;
#pragma unroll
      for (int reg = 0; reg < 4; reg++) {
        const int row = bm + wr + i * 16 + quad * 4 + reg;
        float v = alpha * acc[i][j][reg];
        if (useR) v = fmaf(beta, R[(size_t)row * Nd + col], v);
        if (useR2) v = fmaf(delta, R2[(size_t)row * Nd + col], v);
        if (gamma != 0.0f && row == col) v += gamma;
        C[(size_t)row * Nd + col] = l * v;
      }
    }
  }
}

// ------------------------- small kernels -------------------------
__global__ void k_qsum(const float* __restrict__ Q, float* qsum) {
  __shared__ float red[256];
  const int m = blockIdx.x >> 5, chunk = blockIdx.x & 31;
  const float4* src = (const float4*)(Q + (size_t)m * NN) + (size_t)chunk * 8192 + threadIdx.x;
  float s = 0.f;
#pragma unroll 4
  for (int i = 0; i < 32; i++) {
    const float4 v = src[(size_t)i * 256];
    s += (v.x + v.y) + (v.z + v.w);
  }
  red[threadIdx.x] = s;
  __syncthreads();
  for (int st = 128; st; st >>= 1) {
    if (threadIdx.x < st) red[threadIdx.x] += red[threadIdx.x + st];
    __syncthreads();
  }
  if (threadIdx.x == 0) atomicAdd(&qsum[m], red[0]);
}

__global__ void k_qn(const float* __restrict__ Qbase, const float* __restrict__ qsum, float* __restrict__ S0,
                     int base) {
  size_t id = (size_t)blockIdx.x * 256 + threadIdx.x;
  int b = (int)(id / NN);
  size_t e = id % NN;
  int mi = base + b;
  int i = mi / 3;
  uint32_t nid = (uint32_t)((size_t)mi * NN + e);
  uint32_t pk = nid < NOISE_H ? nid : nid - NOISE_H;
  uint32_t o0, o1;
  tf2x32(pk, pk + NOISE_H, o0, o1);
  uint32_t bits = nid < NOISE_H ? o0 : o1;
  float un = __uint_as_float((bits >> 9) | 0x3F800000u) - 1.0f;
  float coef = 0.01f * qsum[i] * (1.0f / 1048576.0f);
  S0[id] = Qbase[(size_t)i * NN + e] + coef * un;
}

__global__ void k_vinit(float* v) {
  size_t id = (size_t)blockIdx.x * 256 + threadIdx.x;
  uint32_t h = (uint32_t)(id % Nd) * 2654435761u ^ 0x9E3779B9u;
  h ^= h >> 16; h *= 0x85EBCA6Bu; h ^= h >> 13;
  v[id] = (float)(h & 0xFFFFu) / 65536.0f - 0.5f;
}

__global__ __launch_bounds__(256) void k_matvec(const float* __restrict__ Qn, const float* __restrict__ v,
                                                float* __restrict__ w) {
  int b = blockIdx.y;
  const float* M = Qn + (size_t)b * NN;
  const float* vb = v + (size_t)b * Nd;
  int wave = threadIdx.x >> 6, lane = threadIdx.x & 63;
  int row = blockIdx.x * 4 + wave;
  const float* rp = M + (size_t)row * Nd;
  float s = 0.f;
  for (int c = lane; c < Nd; c += 64) s = fmaf(rp[c], vb[c], s);
#pragma unroll
  for (int off = 32; off; off >>= 1) s += __shfl_down(s, off, 64);
  if (lane == 0) w[(size_t)b * Nd + row] = s;
}

__global__ __launch_bounds__(256) void k_matvecT(const float* __restrict__ Qn, const float* __restrict__ w,
                                                 float* __restrict__ u) {
  int b = blockIdx.y;
  const float* M = Qn + (size_t)b * NN;
  const float* wb = w + (size_t)b * Nd;
  int col = blockIdx.x * 256 + threadIdx.x;
  float s = 0.f;
  for (int r = 0; r < Nd; r++) s = fmaf(M[(size_t)r * Nd + col], wb[r], s);
  u[(size_t)b * Nd + col] = s;
}

__global__ void k_normalize(const float* __restrict__ u, float* __restrict__ v, float* theta, float* invth,
                            float* tau, float Gc, int last) {
  int b = blockIdx.x;
  const float* ub = u + (size_t)b * Nd;
  __shared__ float red[256];
  float s = 0.f;
  for (int i = threadIdx.x; i < Nd; i += 256) s = fmaf(ub[i], ub[i], s);
  red[threadIdx.x] = s;
  __syncthreads();
  for (int st = 128; st; st >>= 1) {
    if (threadIdx.x < st) red[threadIdx.x] += red[threadIdx.x + st];
    __syncthreads();
  }
  float n2 = red[0];
  float rn = rsqrtf(n2);
  for (int i = threadIdx.x; i < Nd; i += 256) v[(size_t)b * Nd + i] = ub[i] * rn;
  if (last && threadIdx.x == 0) {
    float th = 1.05f * powf(n2, 0.25f); // wider margin for 5 power iters
    theta[b] = th;
    invth[b] = 1.0f / th;
    tau[b] = th / Gc;
  }
}

__global__ void k_scale(const float* __restrict__ src, const float* __restrict__ invth, float* __restrict__ dst) {
  size_t id = (size_t)blockIdx.x * 256 + threadIdx.x;
  int b = (int)(id / NN);
  dst[id] = src[id] * invth[b];
}

__global__ void k_zcomb(const float* __restrict__ X, const float* __restrict__ Y, const float* __restrict__ tau,
                        float* __restrict__ Z) {
  size_t id = (size_t)blockIdx.x * 256 + threadIdx.x;
  int b = (int)(id / NN);
  Z[id] = tau[b] * (1.5f * X[id] - 0.5f * Y[id]);
}

// dst = ca*A + cb*B + cd*I
__global__ void k_combo(const float* __restrict__ A, const float* __restrict__ B, float* __restrict__ dst,
                        float ca, float cb, float cd) {
  size_t id = (size_t)blockIdx.x * 256 + threadIdx.x;
  size_t e = id % NN;
  int row = (int)(e >> 10), col = (int)(e & 1023);
  float v = ca * A[id] + cb * B[id];
  if (row == col) v += cd;
  dst[id] = v;
}

// out (+)= sum_b 0.5*a0[i,j]*a1[j]*M[b]
__global__ void k_acc(const float* __restrict__ M, const float* __restrict__ a0, const float* __restrict__ a1,
                      float* __restrict__ out, int base, int g, int accum) {
  size_t e = (size_t)blockIdx.x * 256 + threadIdx.x;
  float s = accum ? out[e] : 0.f;
  for (int b = 0; b < g; b++) {
    int gi = base + b, i = gi / 3, j = gi % 3;
    s += 0.5f * a0[i * 3 + j] * a1[j] * M[(size_t)b * NN + e];
  }
  out[e] = s;
}

// ------------------------- host: solver + fits + roots -------------------------
static void solveN(double* M, double* r, double* x, int n) {
  for (int c = 0; c < n; c++) {
    int p = c;
    for (int i = c + 1; i < n; i++)
      if (fabs(M[i * n + c]) > fabs(M[p * n + c])) p = i;
    if (p != c) {
      for (int j = 0; j < n; j++) std::swap(M[c * n + j], M[p * n + j]);
      std::swap(r[c], r[p]);
    }
    double d = M[c * n + c];
    for (int i = c + 1; i < n; i++) {
      double f = M[i * n + c] / d;
      for (int j = c; j < n; j++) M[i * n + j] -= f * M[c * n + j];
      r[i] -= f * r[c];
    }
  }
  for (int c = n - 1; c >= 0; --c) {
    double s = r[c];
    for (int j = c + 1; j < n; j++) s -= M[c * n + j] * x[j];
    x[c] = s / M[c * n + c];
  }
}

static void fit_cheb(double* cq, double aQ, double bQ, double cQ, double Gcomp, double zmax) {
  const double theta_hat = 2660.0;
  const double tau_hat = theta_hat / Gcomp;
  const double wmax = zmax * zmax;
  double Mm[NC * NC] = {0}, rr[NC] = {0}, sol[NC];
  auto add = [&](double z, double t, double wgt) {
    double uu = 2.0 * z * z / wmax - 1.0;
    double T[NC];
    T[0] = 1; T[1] = uu;
    for (int k = 2; k < NC; k++) T[k] = 2.0 * uu * T[k - 1] - T[k - 2];
    double ph[NC];
    for (int k = 0; k < NC; k++) ph[k] = (z / zmax) * T[k];
    for (int a = 0; a < NC; a++) {
      rr[a] += wgt * t * ph[a];
      for (int b = 0; b < NC; b++) Mm[a * NC + b] += wgt * ph[a] * ph[b];
    }
  };
  const int NS = 2600;
  const double lx0 = -5.0, lx1 = log10(1.05);
  for (int si = 0; si < NS; si++) {
    double x = pow(10.0, lx0 + (lx1 - lx0) * si / (NS - 1));
    double y = x;
    for (int q = 0; q < 4; q++) { double y2 = y * y; y = y * (aQ + y2 * (bQ + y2 * cQ)); }
    y = y * (1.5 - 0.5 * y * y);
    double z = tau_hat * y;
    double t = tanh(0.5 * theta_hat * x);
    add(z, t, (t > 0.9999) ? 2.0 : 1.0);
  }
  for (int si = 0; si < 400; si++) { double z = 12.0 + (zmax - 12.0) * si / 399.0; add(z, 1.0, 2.0); }
  solveN(Mm, rr, sol, NC);
  for (int k = 0; k < NC; k++) cq[k] = sol[k] / zmax;
}

static void fit_polish(double* e) {
  // quadratic g(y) = e0 + e1 y + e2 y^2 ~ y^{-1/2} on [0.44, 1.40]
  double M[9] = {0}, r[3] = {0};
  for (int i = 0; i < 400; i++) {
    double y = 0.44 + (1.40 - 0.44) * i / 399.0;
    double t = 1.0 / sqrt(y);
    double ph[3] = {1.0, y, y * y};
    for (int a = 0; a < 3; a++) {
      r[a] += t * ph[a];
      for (int b = 0; b < 3; b++) M[a * 3 + b] += ph[a] * ph[b];
    }
  }
  solveN(M, r, e, 3);
}

static bool poly_roots(const double* a, int deg, std::complex<double>* rt) {
  std::complex<double> z[16];
  for (int i = 0; i < deg; i++) z[i] = std::polar(1.2, 0.37 + 6.2831853 * i / deg);
  for (int it = 0; it < 2000; ++it) {
    double move = 0;
    for (int i = 0; i < deg; i++) {
      std::complex<double> p = a[deg];
      for (int k = deg - 1; k >= 0; --k) p = p * z[i] + a[k];
      std::complex<double> d(a[deg], 0.0);
      for (int j = 0; j < deg; j++)
        if (j != i) d *= (z[i] - z[j]);
      if (std::abs(d) < 1e-300) return false;
      std::complex<double> dz = p / d;
      z[i] -= dz;
      move += std::abs(dz);
    }
    if (move < 1e-13) break;
  }
  for (int i = 0; i < deg; i++) rt[i] = z[i];
  return true;
}

// ------------------------- launch -------------------------
extern "C" void kernel_launch(void* const* d_in, const int* in_sizes, int n_in, void* d_out, int out_size,
                              void* d_ws, size_t ws_size, hipStream_t stream) {
  const float* Us = (const float*)d_in[0];
  const float* Vs = (const float*)d_in[1];
  const float* al0 = (const float*)d_in[2];
  const float* al1 = (const float*)d_in[3];
  float* out = (float*)d_out;

  const double aQ = 3.4445, bQ = -4.7750, cQ = 2.0315;
  const double Gcomp = aQ * aQ * aQ * aQ * 1.5;
  const double zmax = 14.5, wmax = zmax * zmax;
  double cheb[NC], pol[3];
  fit_cheb(cheb, aQ, bQ, cQ, Gcomp, zmax);
  fit_polish(pol);

  // ---- factored form of p(y) = sum cheb[k] T_k(2y/wmax - 1), y = z^2 ----
  double tc[NC][NC] = {{0}};
  tc[0][0] = 1; tc[1][1] = 1;
  for (int k = 2; k < NC; k++)
    for (int j = 0; j < NC; j++) {
      double t = (j > 0 ? 2.0 * tc[k - 1][j - 1] : 0.0) - tc[k - 2][j];
      tc[k][j] = t;
    }
  double au[NC] = {0};
  for (int k = 0; k < NC; k++)
    for (int j = 0; j <= k; j++) au[j] += cheb[k] * tc[k][j];
  int dg = NC - 1;
  double amax = 0;
  for (int j = 0; j < NC; j++) amax = fmax(amax, fabs(au[j]));
  while (dg > 0 && fabs(au[dg]) < 1e-12 * amax) dg--;
  int nquad = 0, nlin = 0;
  double qp[8], qq[8], lin_r0 = 0;
  double sigmaF = 1.0, sgnF = 1.0;
  bool use_factored = false;
  {
    std::complex<double> rt[16];
    if (dg >= 1 && poly_roots(au, dg, rt)) {
      double yr[16];
      int nreal = 0;
      std::complex<double> yc[16];
      int ncm = 0;
      for (int i = 0; i < dg; i++) {
        std::complex<double> y = (rt[i] + 1.0) * (wmax / 2.0);
        if (fabs(y.imag()) < 1e-7 * (1.0 + fabs(y.real()))) yr[nreal++] = y.real();
        else yc[ncm++] = y;
      }
      for (int i = 0; i < ncm; i++)
        if (yc[i].imag() > 0) {
          qp[nquad] = -2.0 * yc[i].real();
          qq[nquad] = std::norm(yc[i]);
          nquad++;
        }
      for (int i = 0; i < nreal; i++)
        for (int j = i + 1; j < nreal; j++)
          if (yr[j] < yr[i]) std::swap(yr[i], yr[j]);
      int i = 0;
      for (; i + 1 < nreal; i += 2) {
        qp[nquad] = -(yr[i] + yr[i + 1]);
        qq[nquad] = yr[i] * yr[i + 1];
        nquad++;
      }
      if (i < nreal) { nlin = 1; lin_r0 = yr[i]; }
      if (2 * nquad + nlin == dg && nquad <= 8) {
        double lead_y = au[dg] * pow(2.0 / wmax, dg);
        sigmaF = pow(fabs(lead_y), 1.0 / dg);
        sgnF = lead_y < 0 ? -1.0 : 1.0;
        double maxerr = 0, maxv = 0;
        for (int s = 0; s <= 256; s++) {
          double y = wmax * s / 256.0;
          double u = 2.0 * y / wmax - 1.0;
          double T0 = 1, T1 = u, pc = cheb[0] + cheb[1] * u;
          for (int k = 2; k < NC; k++) { double T2 = 2 * u * T1 - T0; pc += cheb[k] * T2; T0 = T1; T1 = T2; }
          double pf = nlin ? sgnF * sigmaF * (y - lin_r0) : sgnF;
          for (int qI = 0; qI < nquad; qI++) pf *= sigmaF * sigmaF * (y * y + qp[qI] * y + qq[qI]);
          maxerr = fmax(maxerr, fabs(pf - pc));
          maxv = fmax(maxv, fabs(pc));
        }
        if (maxerr < 1e-4 * fmax(maxv, 1.0)) use_factored = true;
      }
    }
  }

  auto need = [&](int g) -> size_t { return 4ull * (3 * NN + 5ull * g * NN + 3ull * g * Nd + 64); };
  int g = 9;
  if (ws_size < need(9)) g = (ws_size >= need(3)) ? 3 : 1;
  const int groups = 9 / g;

  float* SQ = (float*)d_ws;
  float* S[5];
  for (int k = 0; k < 5; k++) S[k] = SQ + 3 * NN + (size_t)k * g * NN;
  float* pv = SQ + 3 * NN + 5ull * g * NN;
  float* pw = pv + (size_t)g * Nd;
  float* pu = pw + (size_t)g * Nd;
  float* qsum = pu + (size_t)g * Nd;
  float* th = qsum + 3;
  float* invth = th + g;
  float* tau = invth + g;

  auto nt = [&](const float* A, const float* B, const float* R, const float* R2, float* C,
                float al, float be, float ga, float de, const float* lam, int batch) {
    gemm_nt<0><<<dim3(64, 1, batch), 256, 0, stream>>>(A, B, nullptr, R, R2, C, al, be, ga, de, 0.f, 0.f, lam);
  };
  auto ntc = [&](const float* A, const float* B, const float* B2, const float* R2, float* C,
                 float al, float de, float cb1, float cb2, int batch) {
    gemm_nt<1><<<dim3(64, 1, batch), 256, 0, stream>>>(A, B, B2, A, R2, C, al, 0.f, 0.f, de, cb1, cb2, nullptr);
  };
  auto gram = [&](const float* A, const float* B, const float* R, const float* R2, float* C,
                  float al, float be, float ga, float de, const float* lam, int batch) {
    gemm_tn<<<dim3(64, 1, batch), 256, 0, stream>>>(A, B, R, R2, C, al, be, ga, de, lam);
  };

  hipMemsetAsync(qsum, 0, 3 * sizeof(float), stream);
  nt(Us, Vs, Us, Us, SQ, 1.f, 0.f, 0.f, 0.f, nullptr, 3); // Q_i = U_i V_i^T
  k_qsum<<<96, 256, 0, stream>>>(SQ, qsum);

  const int NSTEPS = 10;
  for (int grp = 0; grp < groups; ++grp) {
    const int base = grp * g;
    k_qn<<<g * 4096, 256, 0, stream>>>(SQ, qsum, S[0], base);
    k_vinit<<<(g * Nd) / 256, 256, 0, stream>>>(pv);
    for (int t = 0; t < 5; t++) {
      k_matvec<<<dim3(Nd / 4, g), 256, 0, stream>>>(S[0], pv, pw);
      k_matvecT<<<dim3(Nd / 256, g), 256, 0, stream>>>(S[0], pw, pu);
      k_normalize<<<g, 256, 0, stream>>>(pu, pv, th, invth, tau, (float)Gcomp, t == 4);
    }
    k_scale<<<g * 4096, 256, 0, stream>>>(S[0], invth, S[1]);
    float* Xc = S[1];
    float* Xa = S[2];
    // quintic NS steps: G = X^T X ; Y = X G ; X' = c*YG + b*Y + a*X
    for (int it = 0; it < NSTEPS; ++it) {
      gram(Xc, Xc, Xc, Xc, S[3], 1.f, 0.f, 0.f, 0.f, nullptr, g);            // G
      nt(Xc, S[3], Xc, Xc, S[4], 1.f, 0.f, 0.f, 0.f, nullptr, g);            // Y = X G (G sym)
      if (it == 4) // Z = tau*(1.5X - 0.5Y)
        k_zcomb<<<g * 4096, 256, 0, stream>>>(Xc, S[4], tau, S[0]);
      nt(S[4], S[3], S[4], Xc, Xa, (float)cQ, (float)bQ, 0.f, (float)aQ, nullptr, g);
      std::swap(Xc, Xa);
    }
    // quadratic polish: P = X (e0 I + e1 G + e2 G^2)  [Xc = S1 after even swaps]
    gram(Xc, Xc, Xc, Xc, S[3], 1.f, 0.f, 0.f, 0.f, nullptr, g);                              // G
    nt(S[3], S[3], S[3], S[3], S[4], (float)pol[2], (float)pol[1], (float)pol[0], 0.f, nullptr, g); // W
    nt(Xc, S[4], Xc, Xc, S[2], 1.f, 0.f, 0.f, 0.f, nullptr, g);                              // P = X W
    k_acc<<<4096, 256, 0, stream>>>(S[2], al0, al1, out, base, g, grp > 0);                  // out += w*P
    if (use_factored) {
      const double sg2 = sigmaF * sigmaF;
      gram(S[0], S[0], S[0], S[0], S[3], 1.f, 0.f, 0.f, 0.f, nullptr, g);       // Y = Z^T Z
      nt(S[3], S[3], S[3], S[3], S[4], 1.f, 0.f, 0.f, 0.f, nullptr, g);         // Y2 = Y*Y
      float* Mc = S[1];
      float* Md = S[2];
      int q0 = 0;
      if (nlin) {
        k_combo<<<g * 4096, 256, 0, stream>>>(S[3], S[3], Mc, (float)(sgnF * sigmaF), 0.f,
                                              (float)(-sgnF * sigmaF * lin_r0)); // M = sgn*sig*(Y - r0 I)
      } else {
        // fold first quadratic into elementwise init: M = sgn*sg2*(Y2 + qp0*Y + qq0*I)
        k_combo<<<g * 4096, 256, 0, stream>>>(S[4], S[3], Mc, (float)(sgnF * sg2),
                                              (float)(sgnF * sg2 * qp[0]), (float)(sgnF * sg2 * qq[0]));
        q0 = 1;
      }
      for (int qI = q0; qI < nquad; qI++) {
        // M' = M @ (sg2*Y2 + sg2*qp*Y)^T + sg2*qq*M
        ntc(Mc, S[4], S[3], Mc, Md, 1.f, (float)(sg2 * qq[qI]), (float)sg2, (float)(sg2 * qp[qI]), g);
        std::swap(Mc, Md);
      }
      nt(S[0], Mc, S[0], S[0], Md, 1.f, 0.f, 0.f, 0.f, nullptr, g);             // T = Z q
      k_acc<<<4096, 256, 0, stream>>>(Md, al0, al1, out, base, g, 1);           // out += w*T
    } else {
      // fallback: Clenshaw with NC coeffs (b_{NC-1}, b_{NC-2} folded)
      gram(S[0], S[0], S[0], S[0], S[1], (float)(2.0 / wmax), 0.f, -1.0f, 0.f, nullptr, g);
      float* Wm = S[1];
      nt(Wm, Wm, Wm, Wm, S[2], (float)(4.0 * cheb[NC - 1]), (float)(2.0 * cheb[NC - 2]),
         (float)(cheb[NC - 3] - cheb[NC - 1]), 0.f, nullptr, g);
      nt(Wm, S[2], Wm, Wm, S[4], 2.0f, (float)(-2.0 * cheb[NC - 1]),
         (float)(cheb[NC - 4] - cheb[NC - 2]), 0.f, nullptr, g);
      float* c1 = S[4];
      float* c2 = S[2];
      for (int k = NC - 5; k >= 1; --k) {
        nt(Wm, c1, c2, Wm, c2, 2.0f, -1.0f, (float)cheb[k], 0.f, nullptr, g);
        std::swap(c1, c2);
      }
      nt(Wm, c1, c2, Wm, c2, 1.0f, -1.0f, (float)cheb[0], 0.f, nullptr, g);
      nt(S[0], c2, S[0], S[0], S[3], 1.f, 0.f, 0.f, 0.f, nullptr, g);           // T = Z q
      k_acc<<<4096, 256, 0, stream>>>(S[3], al0, al1, out, base, g, 1);
    }
  }
}